// Round 5
// baseline (248.227 us; speedup 1.0000x reference)
//
#include <hip/hip_runtime.h>

// B=4, C=256, H=W=64 (N=4096). QKV 1x1conv -> spatial attention (softmax over
// j only => independent per-64-key-chunk softmax) -> channel LayerNorm.
// f16 MFMA 32x32x16, fp32 accumulation.
//
// R5 = R4 + bugfix: gemm quarter store only covered 32 of 64 rows (half of
// every Q/K/V tile left unwritten -> absmax 7.03). Now 2 store iterations.
// R4 structure retained: gemm stages weight quarters in LDS at 2 blocks/CU;
// attn drops Vs LDS buffer (V fragments direct from L2/L3), 65 KB LDS ->
// 2 blocks/CU to fill barrier-serialization stalls.

#define CDIM 256
#define NPOS 4096
#define BATCH 4
#define EPSV 1e-5f

typedef _Float16 f16;
typedef __attribute__((ext_vector_type(8))) _Float16 f16x8;
typedef __attribute__((ext_vector_type(4))) float f32x4;
typedef __attribute__((ext_vector_type(16))) float f32x16;

#define WST       264   // f16; 528B = 33*16 -> b128-aligned rows
#define QK_STRIDE 264
#define S_STRIDE  68    // f32; 272B = 17*16
#define P_STRIDE  72
#define DQ_STRIDE 72

// MFMA 32x32x16 f16:
//   A: lane l holds A[m=l&31][k=(l>>5)*8+j]
//   B: lane l holds B[k=(l>>5)*8+j][n=l&31]
//   C/D: lane l, reg r -> col=l&31, row=(r&3)+8*(r>>2)+4*(l>>5)

static __device__ __forceinline__ f16x8 cvt8(const float* __restrict__ p) {
    float4 w0 = *(const float4*)p;
    float4 w1 = *(const float4*)(p + 4);
    f16x8 r;
    r[0] = (f16)w0.x; r[1] = (f16)w0.y; r[2] = (f16)w0.z; r[3] = (f16)w0.w;
    r[4] = (f16)w1.x; r[5] = (f16)w1.y; r[6] = (f16)w1.z; r[7] = (f16)w1.w;
    return r;
}

// ---------------------------------------------------------------------------
// prep: blocks 0..2047 transpose x1/x2 [C][N] fp32 -> [N][C] f16 (64x64 tiles);
// blocks 2048..2059 convert weights fp32 -> f16 [o][c].
// ---------------------------------------------------------------------------
__global__ __launch_bounds__(256, 4) void prep_kernel(
    const float* __restrict__ x1, const float* __restrict__ x2,
    const float* __restrict__ qw, const float* __restrict__ kw,
    const float* __restrict__ vw,
    f16* __restrict__ X1T, f16* __restrict__ X2T, f16* __restrict__ W16)
{
    const int id = blockIdx.x;
    const int t  = threadIdx.x;
    if (id < 2048) {
        __shared__ f16 T[64 * 72];
        const float* xs = (id & 1) ? x2 : x1;
        f16* dst        = (id & 1) ? X2T : X1T;
        const int t2 = id >> 1;
        const int b  = t2 >> 8;
        const int rm = t2 & 255;
        const int c0 = (rm >> 6) * 64;
        const int n0 = (rm & 63) * 64;
        const float* src = xs + ((size_t)b * CDIM + c0) * NPOS + n0;
        const int rr = t >> 6, col = t & 63;
        #pragma unroll
        for (int j = 0; j < 16; ++j) {
            int row = rr + j * 4;
            T[col * 72 + row] = (f16)src[(size_t)row * NPOS + col];
        }
        __syncthreads();
        const int n = t >> 3, lc = (t & 7) * 8;
        f16* d0 = dst + ((size_t)b * NPOS + n0) * CDIM + c0;
        #pragma unroll
        for (int j = 0; j < 2; ++j) {
            int nn = n + j * 32;
            *(f16x8*)(d0 + (size_t)nn * CDIM + lc) = *(const f16x8*)&T[nn * 72 + lc];
        }
    } else {
        const int wblk = id - 2048;          // 0..11
        const int pr = wblk >> 2, h = wblk & 3;
        const float* W = (pr == 0 ? qw : pr == 1 ? kw : vw) + (size_t)h * 64 * CDIM;
        f16* D = W16 + (size_t)pr * CDIM * CDIM + (size_t)h * 64 * CDIM;
        #pragma unroll
        for (int i = 0; i < 8; ++i) {
            int g = t + i * 256;
            int row = g >> 5, col = (g & 31) * 8;
            *(f16x8*)(D + (size_t)row * CDIM + col) = cvt8(W + (size_t)row * CDIM + col);
        }
    }
}

// ---------------------------------------------------------------------------
// gemm: grid 768 = proj(3) x b(4) x ptile(64). Per block: 64 positions x 256
// outputs, processed as 4 weight quarters (64 o-rows) staged in LDS.
// All MFMA operands from LDS; split-k dual accumulators; LDS-assisted
// coalesced stores. LDS 77.8 KB -> 2 blocks/CU.
// Q,K -> [B][N][C] f16; V -> [B][C][N] f16.
// ---------------------------------------------------------------------------
__global__ __launch_bounds__(256, 2) void gemm_kernel(
    const f16* __restrict__ X1T, const f16* __restrict__ X2T,
    const f16* __restrict__ W16,
    const float* __restrict__ qb, const float* __restrict__ kb,
    const float* __restrict__ vb,
    f16* __restrict__ Qg, f16* __restrict__ Kg, f16* __restrict__ Vg)
{
    __shared__ f16 Xs[64 * WST];         // 33792 B  [p][c]
    __shared__ f16 Wh[64 * WST];         // 33792 B  weight quarter [o_l][c]
    __shared__ f16 Ds[64 * DQ_STRIDE];   //  9216 B  output quarter staging
    __shared__ float biasS[256];

    const int id = blockIdx.x;
    const int pr  = id >> 8;             // 0=Q 1=K 2=V
    const int rem = id & 255;
    const int b   = rem >> 6;
    const int p0  = (rem & 63) << 6;
    const f16* XT = (pr == 0) ? X1T : X2T;
    const f16* Wp = W16 + (size_t)pr * CDIM * CDIM;
    const float* bias = pr == 0 ? qb : pr == 1 ? kb : vb;

    const int t = threadIdx.x, w = t >> 6, l = t & 63, lm = l & 31, lh = l >> 5;
    const int pt = w & 1, ot = w >> 1;   // wave tile within 64p x 64o quarter

    biasS[t] = bias[t];
    // stage x tile [64][256] f16, coalesced 1KB/instr
    #pragma unroll
    for (int it = 0; it < 8; ++it) {
        int p = w * 16 + it * 2 + lh;
        *(f16x8*)&Xs[p * WST + lm * 8] =
            *(const f16x8*)(XT + ((size_t)(b * NPOS + p0 + p)) * CDIM + lm * 8);
    }

    for (int q = 0; q < 4; ++q) {
        // stage weight quarter [64][256] f16, coalesced
        #pragma unroll
        for (int i = 0; i < 8; ++i) {
            int g = t + i * 256;
            int row = g >> 5, col = (g & 31) * 8;
            *(f16x8*)&Wh[row * WST + col] =
                *(const f16x8*)(Wp + (size_t)(q * 64 + row) * CDIM + col);
        }
        __syncthreads();   // Wh (and, first iter, Xs) ready; Ds free for rewrite

        // 32x32 tile per wave; split-k dual acc to break the dep chain
        f32x16 accA = {}, accB = {};
        #pragma unroll
        for (int ks = 0; ks < 16; ks += 2) {
            f16x8 x0 = *(const f16x8*)&Xs[(pt * 32 + lm) * WST + ks * 16 + lh * 8];
            f16x8 w0 = *(const f16x8*)&Wh[(ot * 32 + lm) * WST + ks * 16 + lh * 8];
            f16x8 x1v = *(const f16x8*)&Xs[(pt * 32 + lm) * WST + (ks + 1) * 16 + lh * 8];
            f16x8 w1 = *(const f16x8*)&Wh[(ot * 32 + lm) * WST + (ks + 1) * 16 + lh * 8];
            if (pr < 2) {
                accA = __builtin_amdgcn_mfma_f32_32x32x16_f16(x0, w0, accA, 0, 0, 0);
                accB = __builtin_amdgcn_mfma_f32_32x32x16_f16(x1v, w1, accB, 0, 0, 0);
            } else {
                accA = __builtin_amdgcn_mfma_f32_32x32x16_f16(w0, x0, accA, 0, 0, 0);
                accB = __builtin_amdgcn_mfma_f32_32x32x16_f16(w1, x1v, accB, 0, 0, 0);
            }
        }

        // stage output quarter into Ds
        if (pr < 2) {
            // D[p][o_l]: row p_l, col o_l = ot*32+lm
            int o_l = ot * 32 + lm;
            float bv = biasS[q * 64 + o_l];
            #pragma unroll
            for (int r = 0; r < 16; ++r) {
                int p_l = pt * 32 + (r & 3) + 8 * (r >> 2) + 4 * lh;
                Ds[p_l * DQ_STRIDE + o_l] = (f16)(accA[r] + accB[r] + bv);
            }
        } else {
            // D[o_l][p]: row o_l, col p = pt*32+lm
            #pragma unroll
            for (int r = 0; r < 16; ++r) {
                int o_l = ot * 32 + (r & 3) + 8 * (r >> 2) + 4 * lh;
                Ds[o_l * DQ_STRIDE + pt * 32 + lm] =
                    (f16)(accA[r] + accB[r] + biasS[q * 64 + o_l]);
            }
        }
        __syncthreads();   // Ds ready

        // coalesced quarter store: 64 rows x 64 cols f16 = 512 f16x8
        // -> 2 per thread (R4 bug: only 1 -> rows 32..63 never written)
        #pragma unroll
        for (int j = 0; j < 2; ++j) {
            int row = (t >> 3) + j * 32;
            int cc  = (t & 7) * 8;
            f16x8 vdat = *(const f16x8*)&Ds[row * DQ_STRIDE + cc];
            if (pr < 2) {
                f16* Out = (pr == 0) ? Qg : Kg;
                *(f16x8*)(Out + ((size_t)(b * NPOS + p0 + row)) * CDIM + q * 64 + cc) = vdat;
            } else {
                *(f16x8*)(Vg + ((size_t)(b * CDIM + q * 64 + row)) * NPOS + p0 + cc) = vdat;
            }
        }
        // next quarter's Wh stage races only with this store pass (different
        // arrays); Ds rewrite is fenced by the next top barrier.
    }
}

// ---------------------------------------------------------------------------
// attn: grid 256 = (b<<6 | qtile), 256 thr, 2 blocks/CU (LDS 65 KB).
// Q fragments in registers; K prefetched one chunk ahead; V fragments read
// directly from global (L2/L3) with latency hidden behind S+softmax.
// ---------------------------------------------------------------------------
__global__ __launch_bounds__(256, 2) void attn_kernel(
    const f16* __restrict__ Qg, const f16* __restrict__ Kg, const f16* __restrict__ Vg,
    const float* __restrict__ ln_w, const float* __restrict__ ln_b,
    float* __restrict__ out)
{
    __shared__ f16   Ks[64 * QK_STRIDE];    // 33792 B  [key][c]
    __shared__ float Ss[64 * S_STRIDE];     // 17408 B  [p][key]
    __shared__ f16   Ps[64 * P_STRIDE];     //  9216 B  [p][key]
    __shared__ float lnw_s[256], lnb_s[256];
    __shared__ float redS[4 * 64], redQ[4 * 64], mu_s[64], rs_s[64];

    const int t  = threadIdx.x;
    const int b  = blockIdx.x >> 6;
    const int p0 = (blockIdx.x & 63) << 6;
    const int w  = t >> 6;
    const int l  = t & 63;
    const int lm = l & 31;
    const int lh = l >> 5;

    lnw_s[t] = ln_w[t];
    lnb_s[t] = ln_b[t];

    const int spt = w & 1;    // wave's S tile: p-tile spt, key-tile skt
    const int skt = w >> 1;

    // Q fragments for this wave's p-tile (L2-warm).
    f16x8 qf[16];
    {
        const f16* qptr = Qg + (size_t)(b * NPOS + p0 + spt * 32 + lm) * CDIM + lh * 8;
        #pragma unroll
        for (int ks = 0; ks < 16; ++ks) qf[ks] = *(const f16x8*)(qptr + ks * 16);
    }

    // K prefetch registers (one chunk ahead).
    const int kr = t >> 5, koff = (t & 31) * 8;
    f16x8 kreg[8];
    auto issue_k = [&](int ch) {
        const int i0 = ch * 64;
        #pragma unroll
        for (int r = 0; r < 8; ++r)
            kreg[r] = *(const f16x8*)(Kg + (size_t)(b * NPOS + i0 + r * 8 + kr) * CDIM + koff);
    };
    issue_k(0);

    // V fragment base for PV: A[m=c][k=key], c rows = w*64 + {0,32} + lm
    const f16* vbase0 = Vg + (size_t)(b * CDIM + w * 64 + lm) * NPOS;
    const f16* vbase1 = Vg + (size_t)(b * CDIM + w * 64 + 32 + lm) * NPOS;

    f32x16 facc[4] = {};      // persistent F acc: [i=c-tile(2)][j=p-tile(2)]

    for (int ch = 0; ch < 64; ++ch) {
        const int i0 = ch * 64;
        #pragma unroll
        for (int r = 0; r < 8; ++r)
            *(f16x8*)&Ks[(r * 8 + kr) * QK_STRIDE + koff] = kreg[r];
        __syncthreads();   // A: Ks ready; prev PV done (Ps free)

        // issue this chunk's V fragment loads (consumed ~600+ cyc later in PV)
        f16x8 vf0[4], vf1[4];
        #pragma unroll
        for (int ks = 0; ks < 4; ++ks) {
            vf0[ks] = *(const f16x8*)(vbase0 + i0 + ks * 16 + lh * 8);
            vf1[ks] = *(const f16x8*)(vbase1 + i0 + ks * 16 + lh * 8);
        }

        // S = Q K^T
        f32x16 sacc = {};
        #pragma unroll
        for (int ks = 0; ks < 16; ++ks) {
            f16x8 bb = *(const f16x8*)&Ks[(skt * 32 + lm) * QK_STRIDE + ks * 16 + lh * 8];
            sacc = __builtin_amdgcn_mfma_f32_32x32x16_f16(qf[ks], bb, sacc, 0, 0, 0);
        }
        #pragma unroll
        for (int r = 0; r < 16; ++r) {
            int row = (r & 3) + 8 * (r >> 2) + 4 * lh;
            Ss[(spt * 32 + row) * S_STRIDE + skt * 32 + lm] = sacc[r];
        }
        __syncthreads();   // B: Ss ready

        // softmax per row: 4 threads/row x 16 elems
        {
            const int r  = t >> 2;
            const int sg = (t & 3) * 16;
            const float* srow = &Ss[r * S_STRIDE + sg];
            float v[16];
            f32x4 a0 = *(const f32x4*)(srow);
            f32x4 a1 = *(const f32x4*)(srow + 4);
            f32x4 a2 = *(const f32x4*)(srow + 8);
            f32x4 a3 = *(const f32x4*)(srow + 12);
            v[0]=a0[0]; v[1]=a0[1]; v[2]=a0[2]; v[3]=a0[3];
            v[4]=a1[0]; v[5]=a1[1]; v[6]=a1[2]; v[7]=a1[3];
            v[8]=a2[0]; v[9]=a2[1]; v[10]=a2[2]; v[11]=a2[3];
            v[12]=a3[0]; v[13]=a3[1]; v[14]=a3[2]; v[15]=a3[3];
            float m = v[0];
            #pragma unroll
            for (int i = 1; i < 16; ++i) m = fmaxf(m, v[i]);
            m = fmaxf(m, __shfl_xor(m, 1));
            m = fmaxf(m, __shfl_xor(m, 2));
            float s = 0.f;
            #pragma unroll
            for (int i = 0; i < 16; ++i) { float e = __expf(v[i] - m); v[i] = e; s += e; }
            s += __shfl_xor(s, 1);
            s += __shfl_xor(s, 2);
            float inv = __builtin_amdgcn_rcpf(s);
            f16x8 h0, h1;
            #pragma unroll
            for (int i = 0; i < 8; ++i) { h0[i] = (f16)(v[i] * inv); h1[i] = (f16)(v[i + 8] * inv); }
            *(f16x8*)&Ps[r * P_STRIDE + sg]     = h0;
            *(f16x8*)&Ps[r * P_STRIDE + sg + 8] = h1;
        }
        __syncthreads();   // C: Ps ready

        if (ch < 63) issue_k(ch + 1);   // hidden behind PV

        // F += V * P^T (V fragments from registers, loaded from global above)
        #pragma unroll
        for (int ks = 0; ks < 4; ++ks) {
            f16x8 bp0 = *(const f16x8*)&Ps[lm * P_STRIDE + ks * 16 + lh * 8];
            f16x8 bp1 = *(const f16x8*)&Ps[(32 + lm) * P_STRIDE + ks * 16 + lh * 8];
            facc[0] = __builtin_amdgcn_mfma_f32_32x32x16_f16(vf0[ks], bp0, facc[0], 0, 0, 0);
            facc[1] = __builtin_amdgcn_mfma_f32_32x32x16_f16(vf0[ks], bp1, facc[1], 0, 0, 0);
            facc[2] = __builtin_amdgcn_mfma_f32_32x32x16_f16(vf1[ks], bp0, facc[2], 0, 0, 0);
            facc[3] = __builtin_amdgcn_mfma_f32_32x32x16_f16(vf1[ks], bp1, facc[3], 0, 0, 0);
        }
    }

    // fused LayerNorm over c per position p
    float ps0 = 0.f, ps1 = 0.f, pq0 = 0.f, pq1 = 0.f;
    #pragma unroll
    for (int ii = 0; ii < 2; ++ii) {
        #pragma unroll
        for (int r = 0; r < 16; ++r) {
            float a = facc[ii * 2 + 0][r];
            float c = facc[ii * 2 + 1][r];
            ps0 += a; pq0 += a * a;
            ps1 += c; pq1 += c * c;
        }
    }
    ps0 += __shfl_xor(ps0, 32); pq0 += __shfl_xor(pq0, 32);
    ps1 += __shfl_xor(ps1, 32); pq1 += __shfl_xor(pq1, 32);
    if (lh == 0) {
        redS[w * 64 + lm] = ps0;        redQ[w * 64 + lm] = pq0;
        redS[w * 64 + 32 + lm] = ps1;   redQ[w * 64 + 32 + lm] = pq1;
    }
    __syncthreads();
    if (t < 64) {
        float s = redS[t] + redS[64 + t] + redS[128 + t] + redS[192 + t];
        float q = redQ[t] + redQ[64 + t] + redQ[128 + t] + redQ[192 + t];
        float mean = s * (1.0f / 256.0f);
        float var  = q * (1.0f / 256.0f) - mean * mean;
        mu_s[t] = mean;
        rs_s[t] = rsqrtf(var + EPSV);
    }
    __syncthreads();
    #pragma unroll
    for (int ii = 0; ii < 2; ++ii) {
        #pragma unroll
        for (int jj = 0; jj < 2; ++jj) {
            int p = jj * 32 + lm;
            float mu = mu_s[p], rs = rs_s[p];
            float* dst = out + (size_t)b * CDIM * NPOS + p0 + p;
            #pragma unroll
            for (int r = 0; r < 16; ++r) {
                int c = w * 64 + ii * 32 + (r & 3) + 8 * (r >> 2) + 4 * lh;
                float vL = facc[ii * 2 + jj][r];
                dst[(size_t)c * NPOS] = (vL - mu) * rs * lnw_s[c] + lnb_s[c];
            }
        }
    }
}

// ---------------------------------------------------------------------------
extern "C" void kernel_launch(void* const* d_in, const int* in_sizes, int n_in,
                              void* d_out, int out_size, void* d_ws, size_t ws_size,
                              hipStream_t stream)
{
    const float* x1  = (const float*)d_in[0];
    const float* x2  = (const float*)d_in[1];
    const float* qw  = (const float*)d_in[2];
    const float* qb  = (const float*)d_in[3];
    const float* kw  = (const float*)d_in[4];
    const float* kb  = (const float*)d_in[5];
    const float* vw  = (const float*)d_in[6];
    const float* vb  = (const float*)d_in[7];
    const float* lnw = (const float*)d_in[8];
    const float* lnb = (const float*)d_in[9];

    const size_t tsz = (size_t)BATCH * NPOS * CDIM;
    f16* Qg  = (f16*)d_ws;
    f16* Kg  = Qg + tsz;
    f16* Vg  = Kg + tsz;
    f16* X1T = Vg + tsz;
    f16* X2T = X1T + tsz;
    f16* W16 = X2T + tsz;

    prep_kernel<<<2060, 256, 0, stream>>>(x1, x2, qw, kw, vw, X1T, X2T, W16);
    gemm_kernel<<<768, 256, 0, stream>>>(X1T, X2T, W16, qb, kb, vb, Qg, Kg, Vg);
    attn_kernel<<<256, 256, 0, stream>>>(Qg, Kg, Vg, lnw, lnb, (float*)d_out);
}

// Round 6
// 229.906 us; speedup vs baseline: 1.0797x; 1.0797x over previous
//
#include <hip/hip_runtime.h>

// B=4, C=256, H=W=64 (N=4096). QKV 1x1conv -> spatial attention (softmax over
// j only => independent per-64-key-chunk softmax) -> channel LayerNorm.
// f16 MFMA 32x32x16, fp32 accumulation.
//
// R6: attn only. 512-thread blocks, two wave-groups each processing its own
// key-chunk stream (private Ks/Ss/Ps), shared barriers -> 2 waves/SIMD fill
// phase stalls; barriers per chunk halve. Group-1 F accumulator merged via
// LDS (aliased over Ks) before fused LayerNorm. prep/gemm identical to R5.

#define CDIM 256
#define NPOS 4096
#define BATCH 4
#define EPSV 1e-5f

typedef _Float16 f16;
typedef __attribute__((ext_vector_type(8))) _Float16 f16x8;
typedef __attribute__((ext_vector_type(4))) float f32x4;
typedef __attribute__((ext_vector_type(16))) float f32x16;

#define WST       264   // f16; 528B = 33*16 -> b128-aligned rows
#define QK_STRIDE 264
#define S_STRIDE  68    // f32; 272B = 17*16
#define P_STRIDE  72
#define DQ_STRIDE 72
#define FT_STRIDE 66    // f32 merge buffer; (2c+p)%32 -> 2-way only

// MFMA 32x32x16 f16:
//   A: lane l holds A[m=l&31][k=(l>>5)*8+j]
//   B: lane l holds B[k=(l>>5)*8+j][n=l&31]
//   C/D: lane l, reg r -> col=l&31, row=(r&3)+8*(r>>2)+4*(l>>5)

static __device__ __forceinline__ f16x8 cvt8(const float* __restrict__ p) {
    float4 w0 = *(const float4*)p;
    float4 w1 = *(const float4*)(p + 4);
    f16x8 r;
    r[0] = (f16)w0.x; r[1] = (f16)w0.y; r[2] = (f16)w0.z; r[3] = (f16)w0.w;
    r[4] = (f16)w1.x; r[5] = (f16)w1.y; r[6] = (f16)w1.z; r[7] = (f16)w1.w;
    return r;
}

// ---------------------------------------------------------------------------
// prep: blocks 0..2047 transpose x1/x2 [C][N] fp32 -> [N][C] f16 (64x64 tiles);
// blocks 2048..2059 convert weights fp32 -> f16 [o][c].  (unchanged from R5)
// ---------------------------------------------------------------------------
__global__ __launch_bounds__(256, 4) void prep_kernel(
    const float* __restrict__ x1, const float* __restrict__ x2,
    const float* __restrict__ qw, const float* __restrict__ kw,
    const float* __restrict__ vw,
    f16* __restrict__ X1T, f16* __restrict__ X2T, f16* __restrict__ W16)
{
    const int id = blockIdx.x;
    const int t  = threadIdx.x;
    if (id < 2048) {
        __shared__ f16 T[64 * 72];
        const float* xs = (id & 1) ? x2 : x1;
        f16* dst        = (id & 1) ? X2T : X1T;
        const int t2 = id >> 1;
        const int b  = t2 >> 8;
        const int rm = t2 & 255;
        const int c0 = (rm >> 6) * 64;
        const int n0 = (rm & 63) * 64;
        const float* src = xs + ((size_t)b * CDIM + c0) * NPOS + n0;
        const int rr = t >> 6, col = t & 63;
        #pragma unroll
        for (int j = 0; j < 16; ++j) {
            int row = rr + j * 4;
            T[col * 72 + row] = (f16)src[(size_t)row * NPOS + col];
        }
        __syncthreads();
        const int n = t >> 3, lc = (t & 7) * 8;
        f16* d0 = dst + ((size_t)b * NPOS + n0) * CDIM + c0;
        #pragma unroll
        for (int j = 0; j < 2; ++j) {
            int nn = n + j * 32;
            *(f16x8*)(d0 + (size_t)nn * CDIM + lc) = *(const f16x8*)&T[nn * 72 + lc];
        }
    } else {
        const int wblk = id - 2048;          // 0..11
        const int pr = wblk >> 2, h = wblk & 3;
        const float* W = (pr == 0 ? qw : pr == 1 ? kw : vw) + (size_t)h * 64 * CDIM;
        f16* D = W16 + (size_t)pr * CDIM * CDIM + (size_t)h * 64 * CDIM;
        #pragma unroll
        for (int i = 0; i < 8; ++i) {
            int g = t + i * 256;
            int row = g >> 5, col = (g & 31) * 8;
            *(f16x8*)(D + (size_t)row * CDIM + col) = cvt8(W + (size_t)row * CDIM + col);
        }
    }
}

// ---------------------------------------------------------------------------
// gemm: unchanged from R5 (proven correct). 768 blocks, weight quarters in
// LDS, split-k dual acc, LDS-assisted coalesced stores.
// ---------------------------------------------------------------------------
__global__ __launch_bounds__(256, 2) void gemm_kernel(
    const f16* __restrict__ X1T, const f16* __restrict__ X2T,
    const f16* __restrict__ W16,
    const float* __restrict__ qb, const float* __restrict__ kb,
    const float* __restrict__ vb,
    f16* __restrict__ Qg, f16* __restrict__ Kg, f16* __restrict__ Vg)
{
    __shared__ f16 Xs[64 * WST];
    __shared__ f16 Wh[64 * WST];
    __shared__ f16 Ds[64 * DQ_STRIDE];
    __shared__ float biasS[256];

    const int id = blockIdx.x;
    const int pr  = id >> 8;
    const int rem = id & 255;
    const int b   = rem >> 6;
    const int p0  = (rem & 63) << 6;
    const f16* XT = (pr == 0) ? X1T : X2T;
    const f16* Wp = W16 + (size_t)pr * CDIM * CDIM;
    const float* bias = pr == 0 ? qb : pr == 1 ? kb : vb;

    const int t = threadIdx.x, w = t >> 6, l = t & 63, lm = l & 31, lh = l >> 5;
    const int pt = w & 1, ot = w >> 1;

    biasS[t] = bias[t];
    #pragma unroll
    for (int it = 0; it < 8; ++it) {
        int p = w * 16 + it * 2 + lh;
        *(f16x8*)&Xs[p * WST + lm * 8] =
            *(const f16x8*)(XT + ((size_t)(b * NPOS + p0 + p)) * CDIM + lm * 8);
    }

    for (int q = 0; q < 4; ++q) {
        #pragma unroll
        for (int i = 0; i < 8; ++i) {
            int g = t + i * 256;
            int row = g >> 5, col = (g & 31) * 8;
            *(f16x8*)&Wh[row * WST + col] =
                *(const f16x8*)(Wp + (size_t)(q * 64 + row) * CDIM + col);
        }
        __syncthreads();

        f32x16 accA = {}, accB = {};
        #pragma unroll
        for (int ks = 0; ks < 16; ks += 2) {
            f16x8 x0 = *(const f16x8*)&Xs[(pt * 32 + lm) * WST + ks * 16 + lh * 8];
            f16x8 w0 = *(const f16x8*)&Wh[(ot * 32 + lm) * WST + ks * 16 + lh * 8];
            f16x8 x1v = *(const f16x8*)&Xs[(pt * 32 + lm) * WST + (ks + 1) * 16 + lh * 8];
            f16x8 w1 = *(const f16x8*)&Wh[(ot * 32 + lm) * WST + (ks + 1) * 16 + lh * 8];
            if (pr < 2) {
                accA = __builtin_amdgcn_mfma_f32_32x32x16_f16(x0, w0, accA, 0, 0, 0);
                accB = __builtin_amdgcn_mfma_f32_32x32x16_f16(x1v, w1, accB, 0, 0, 0);
            } else {
                accA = __builtin_amdgcn_mfma_f32_32x32x16_f16(w0, x0, accA, 0, 0, 0);
                accB = __builtin_amdgcn_mfma_f32_32x32x16_f16(w1, x1v, accB, 0, 0, 0);
            }
        }

        if (pr < 2) {
            int o_l = ot * 32 + lm;
            float bv = biasS[q * 64 + o_l];
            #pragma unroll
            for (int r = 0; r < 16; ++r) {
                int p_l = pt * 32 + (r & 3) + 8 * (r >> 2) + 4 * lh;
                Ds[p_l * DQ_STRIDE + o_l] = (f16)(accA[r] + accB[r] + bv);
            }
        } else {
            #pragma unroll
            for (int r = 0; r < 16; ++r) {
                int o_l = ot * 32 + (r & 3) + 8 * (r >> 2) + 4 * lh;
                Ds[o_l * DQ_STRIDE + pt * 32 + lm] =
                    (f16)(accA[r] + accB[r] + biasS[q * 64 + o_l]);
            }
        }
        __syncthreads();

        #pragma unroll
        for (int j = 0; j < 2; ++j) {
            int row = (t >> 3) + j * 32;
            int cc  = (t & 7) * 8;
            f16x8 vdat = *(const f16x8*)&Ds[row * DQ_STRIDE + cc];
            if (pr < 2) {
                f16* Out = (pr == 0) ? Qg : Kg;
                *(f16x8*)(Out + ((size_t)(b * NPOS + p0 + row)) * CDIM + q * 64 + cc) = vdat;
            } else {
                *(f16x8*)(Vg + ((size_t)(b * CDIM + q * 64 + row)) * NPOS + p0 + cc) = vdat;
            }
        }
    }
}

// ---------------------------------------------------------------------------
// attn: grid 256 = (b<<6 | qtile), 512 thr = 2 wave-groups. Group g processes
// chunks 2*it+g with private Ks/Ss/Ps; shared barriers (phases lockstep) ->
// 2 waves/SIMD per phase. Group-1 facc merged via LDS Ftmp (aliases Ks),
// then group 0 does fused LayerNorm. LDS ~125 KB.
// ---------------------------------------------------------------------------
__global__ __launch_bounds__(512, 1) void attn_kernel(
    const f16* __restrict__ Qg, const f16* __restrict__ Kg, const f16* __restrict__ Vg,
    const float* __restrict__ ln_w, const float* __restrict__ ln_b,
    float* __restrict__ out)
{
    __shared__ f16   Ks[2][64 * QK_STRIDE];   // 67584 B (also aliased as Ftmp)
    __shared__ float Ss[2][64 * S_STRIDE];    // 34816 B
    __shared__ f16   Ps[2][64 * P_STRIDE];    // 18432 B
    __shared__ float lnw_s[256], lnb_s[256];
    __shared__ float redS[4 * 64], redQ[4 * 64], mu_s[64], rs_s[64];

    const int t   = threadIdx.x;
    const int b   = blockIdx.x >> 6;
    const int p0  = (blockIdx.x & 63) << 6;
    const int w   = t >> 6;          // 0..7
    const int g   = t >> 8;          // wave-group 0/1
    const int wl  = w & 3;           // wave within group
    const int tl  = t & 255;         // thread within group
    const int l   = t & 63;
    const int lm  = l & 31;
    const int lh  = l >> 5;

    if (t < 256) { lnw_s[t] = ln_w[t]; lnb_s[t] = ln_b[t]; }

    const int spt = wl & 1;          // wave's S tile: p-tile spt, key-tile skt
    const int skt = wl >> 1;

    // Q fragments for this wave's p-tile (L2-warm; dup across groups is fine).
    f16x8 qf[16];
    {
        const f16* qptr = Qg + (size_t)(b * NPOS + p0 + spt * 32 + lm) * CDIM + lh * 8;
        #pragma unroll
        for (int ks = 0; ks < 16; ++ks) qf[ks] = *(const f16x8*)(qptr + ks * 16);
    }

    // K prefetch registers (group-local chunk stream: g, g+2, g+4, ...).
    const int kr = tl >> 5, koff = (tl & 31) * 8;
    f16x8 kreg[8];
    auto issue_k = [&](int ch) {
        const int i0 = ch * 64;
        #pragma unroll
        for (int r = 0; r < 8; ++r)
            kreg[r] = *(const f16x8*)(Kg + (size_t)(b * NPOS + i0 + r * 8 + kr) * CDIM + koff);
    };
    issue_k(g);

    // V fragment bases: wave's c-strip = wl*64 + {0,32}
    const f16* vbase0 = Vg + (size_t)(b * CDIM + wl * 64 + lm) * NPOS;
    const f16* vbase1 = Vg + (size_t)(b * CDIM + wl * 64 + 32 + lm) * NPOS;

    f32x16 facc[4] = {};      // per-wave F acc: [i=c-tile(2)][j=p-tile(2)]

    for (int it = 0; it < 32; ++it) {
        const int ch = it * 2 + g;
        const int i0 = ch * 64;

        // commit prefetched K to group's LDS buffer
        #pragma unroll
        for (int r = 0; r < 8; ++r)
            *(f16x8*)&Ks[g][(r * 8 + kr) * QK_STRIDE + koff] = kreg[r];
        __syncthreads();   // A: Ks ready; prev PV done (Ps free)

        // issue this chunk's V fragment loads (hidden behind S-phase)
        f16x8 vf0[4], vf1[4];
        #pragma unroll
        for (int ks = 0; ks < 4; ++ks) {
            vf0[ks] = *(const f16x8*)(vbase0 + i0 + ks * 16 + lh * 8);
            vf1[ks] = *(const f16x8*)(vbase1 + i0 + ks * 16 + lh * 8);
        }

        // S = Q K^T
        f32x16 sacc = {};
        #pragma unroll
        for (int ks = 0; ks < 16; ++ks) {
            f16x8 bb = *(const f16x8*)&Ks[g][(skt * 32 + lm) * QK_STRIDE + ks * 16 + lh * 8];
            sacc = __builtin_amdgcn_mfma_f32_32x32x16_f16(qf[ks], bb, sacc, 0, 0, 0);
        }
        #pragma unroll
        for (int r = 0; r < 16; ++r) {
            int row = (r & 3) + 8 * (r >> 2) + 4 * lh;
            Ss[g][(spt * 32 + row) * S_STRIDE + skt * 32 + lm] = sacc[r];
        }
        __syncthreads();   // B: Ss ready

        // softmax per row (group-local): 4 threads/row x 16 elems
        {
            const int r  = tl >> 2;
            const int sg = (tl & 3) * 16;
            const float* srow = &Ss[g][r * S_STRIDE + sg];
            float v[16];
            f32x4 a0 = *(const f32x4*)(srow);
            f32x4 a1 = *(const f32x4*)(srow + 4);
            f32x4 a2 = *(const f32x4*)(srow + 8);
            f32x4 a3 = *(const f32x4*)(srow + 12);
            v[0]=a0[0]; v[1]=a0[1]; v[2]=a0[2]; v[3]=a0[3];
            v[4]=a1[0]; v[5]=a1[1]; v[6]=a1[2]; v[7]=a1[3];
            v[8]=a2[0]; v[9]=a2[1]; v[10]=a2[2]; v[11]=a2[3];
            v[12]=a3[0]; v[13]=a3[1]; v[14]=a3[2]; v[15]=a3[3];
            float m = v[0];
            #pragma unroll
            for (int i = 1; i < 16; ++i) m = fmaxf(m, v[i]);
            m = fmaxf(m, __shfl_xor(m, 1));
            m = fmaxf(m, __shfl_xor(m, 2));
            float s = 0.f;
            #pragma unroll
            for (int i = 0; i < 16; ++i) { float e = __expf(v[i] - m); v[i] = e; s += e; }
            s += __shfl_xor(s, 1);
            s += __shfl_xor(s, 2);
            float inv = __builtin_amdgcn_rcpf(s);
            f16x8 h0, h1;
            #pragma unroll
            for (int i = 0; i < 8; ++i) { h0[i] = (f16)(v[i] * inv); h1[i] = (f16)(v[i + 8] * inv); }
            *(f16x8*)&Ps[g][r * P_STRIDE + sg]     = h0;
            *(f16x8*)&Ps[g][r * P_STRIDE + sg + 8] = h1;
        }
        __syncthreads();   // C: Ps ready

        if (it < 31) issue_k(ch + 2);   // hidden behind PV

        // F += V * P^T
        #pragma unroll
        for (int ks = 0; ks < 4; ++ks) {
            f16x8 bp0 = *(const f16x8*)&Ps[g][lm * P_STRIDE + ks * 16 + lh * 8];
            f16x8 bp1 = *(const f16x8*)&Ps[g][(32 + lm) * P_STRIDE + ks * 16 + lh * 8];
            facc[0] = __builtin_amdgcn_mfma_f32_32x32x16_f16(vf0[ks], bp0, facc[0], 0, 0, 0);
            facc[1] = __builtin_amdgcn_mfma_f32_32x32x16_f16(vf0[ks], bp1, facc[1], 0, 0, 0);
            facc[2] = __builtin_amdgcn_mfma_f32_32x32x16_f16(vf1[ks], bp0, facc[2], 0, 0, 0);
            facc[3] = __builtin_amdgcn_mfma_f32_32x32x16_f16(vf1[ks], bp1, facc[3], 0, 0, 0);
        }
    }

    // ---- merge group 1's facc into group 0 via LDS Ftmp (aliases Ks) ----
    float* Ftmp = (float*)&Ks[0][0];   // [256c][FT_STRIDE] fp32 = 67584 B
    __syncthreads();   // D: all PV done (Ks dead, Ps reads done)
    if (g == 1) {
        #pragma unroll
        for (int ii = 0; ii < 2; ++ii)
            #pragma unroll
            for (int jj = 0; jj < 2; ++jj)
                #pragma unroll
                for (int r = 0; r < 16; ++r) {
                    int c = wl * 64 + ii * 32 + (r & 3) + 8 * (r >> 2) + 4 * lh;
                    int p = jj * 32 + lm;
                    Ftmp[c * FT_STRIDE + p] = facc[ii * 2 + jj][r];
                }
    }
    __syncthreads();   // E
    float ps0 = 0.f, ps1 = 0.f, pq0 = 0.f, pq1 = 0.f;
    if (g == 0) {
        #pragma unroll
        for (int ii = 0; ii < 2; ++ii)
            #pragma unroll
            for (int jj = 0; jj < 2; ++jj)
                #pragma unroll
                for (int r = 0; r < 16; ++r) {
                    int c = wl * 64 + ii * 32 + (r & 3) + 8 * (r >> 2) + 4 * lh;
                    int p = jj * 32 + lm;
                    facc[ii * 2 + jj][r] += Ftmp[c * FT_STRIDE + p];
                }
        // per-wave LN partial sums
        #pragma unroll
        for (int ii = 0; ii < 2; ++ii) {
            #pragma unroll
            for (int r = 0; r < 16; ++r) {
                float a = facc[ii * 2 + 0][r];
                float c = facc[ii * 2 + 1][r];
                ps0 += a; pq0 += a * a;
                ps1 += c; pq1 += c * c;
            }
        }
        ps0 += __shfl_xor(ps0, 32); pq0 += __shfl_xor(pq0, 32);
        ps1 += __shfl_xor(ps1, 32); pq1 += __shfl_xor(pq1, 32);
        if (lh == 0) {
            redS[wl * 64 + lm] = ps0;        redQ[wl * 64 + lm] = pq0;
            redS[wl * 64 + 32 + lm] = ps1;   redQ[wl * 64 + 32 + lm] = pq1;
        }
    }
    __syncthreads();   // F
    if (t < 64) {
        float s = redS[t] + redS[64 + t] + redS[128 + t] + redS[192 + t];
        float q = redQ[t] + redQ[64 + t] + redQ[128 + t] + redQ[192 + t];
        float mean = s * (1.0f / 256.0f);
        float var  = q * (1.0f / 256.0f) - mean * mean;
        mu_s[t] = mean;
        rs_s[t] = rsqrtf(var + EPSV);
    }
    __syncthreads();   // G
    if (g == 0) {
        #pragma unroll
        for (int ii = 0; ii < 2; ++ii) {
            #pragma unroll
            for (int jj = 0; jj < 2; ++jj) {
                int p = jj * 32 + lm;
                float mu = mu_s[p], rs = rs_s[p];
                float* dst = out + (size_t)b * CDIM * NPOS + p0 + p;
                #pragma unroll
                for (int r = 0; r < 16; ++r) {
                    int c = wl * 64 + ii * 32 + (r & 3) + 8 * (r >> 2) + 4 * lh;
                    float vL = facc[ii * 2 + jj][r];
                    dst[(size_t)c * NPOS] = (vL - mu) * rs * lnw_s[c] + lnb_s[c];
                }
            }
        }
    }
}

// ---------------------------------------------------------------------------
extern "C" void kernel_launch(void* const* d_in, const int* in_sizes, int n_in,
                              void* d_out, int out_size, void* d_ws, size_t ws_size,
                              hipStream_t stream)
{
    const float* x1  = (const float*)d_in[0];
    const float* x2  = (const float*)d_in[1];
    const float* qw  = (const float*)d_in[2];
    const float* qb  = (const float*)d_in[3];
    const float* kw  = (const float*)d_in[4];
    const float* kb  = (const float*)d_in[5];
    const float* vw  = (const float*)d_in[6];
    const float* vb  = (const float*)d_in[7];
    const float* lnw = (const float*)d_in[8];
    const float* lnb = (const float*)d_in[9];

    const size_t tsz = (size_t)BATCH * NPOS * CDIM;
    f16* Qg  = (f16*)d_ws;
    f16* Kg  = Qg + tsz;
    f16* Vg  = Kg + tsz;
    f16* X1T = Vg + tsz;
    f16* X2T = X1T + tsz;
    f16* W16 = X2T + tsz;

    prep_kernel<<<2060, 256, 0, stream>>>(x1, x2, qw, kw, vw, X1T, X2T, W16);
    gemm_kernel<<<768, 256, 0, stream>>>(X1T, X2T, W16, qb, kb, vb, Qg, Kg, Vg);
    attn_kernel<<<256, 512, 0, stream>>>(Qg, Kg, Vg, lnw, lnb, (float*)d_out);
}